// Round 2
// baseline (380.786 us; speedup 1.0000x reference)
//
#include <hip/hip_runtime.h>

#define N_SRC_C 100000
#define N_OUT_C 50000
#define N_EDGE_C 500000
#define DIM 128

// ---------------------------------------------------------------------------
// 1) degree accumulation: deg[row_e] += w_e   (self-loop "+1" added in k_dinv)
// ---------------------------------------------------------------------------
__global__ __launch_bounds__(256) void k_deg(const int* __restrict__ erow,
                                             const float* __restrict__ ew,
                                             float* __restrict__ deg) {
    int i = blockIdx.x * 256 + threadIdx.x;
    if (i < N_EDGE_C) {
        unsafeAtomicAdd(&deg[erow[i]], ew[i]);
    }
}

// ---------------------------------------------------------------------------
// 2) dinv[i] = (1 + deg[i])^-0.5, in place
// ---------------------------------------------------------------------------
__global__ __launch_bounds__(256) void k_dinv(float* __restrict__ deg) {
    int i = blockIdx.x * 256 + threadIdx.x;
    if (i < N_OUT_C) deg[i] = rsqrtf(1.0f + deg[i]);
}

// ---------------------------------------------------------------------------
// 3) xw[0:50000] = x[0:50000] @ W   (fp32 VALU GEMM, M=50000 N=128 K=128)
//    block: 64 rows x 128 cols; 256 threads; each thread 4 rows x 8 cols.
//    xs row stride 132 floats (16B-aligned float4 staging; compute reads are
//    broadcast-within-16-lane groups, <=2-way bank aliasing = free).
// ---------------------------------------------------------------------------
__global__ __launch_bounds__(256) void k_gemm(const float* __restrict__ x,
                                              const float* __restrict__ W,
                                              float* __restrict__ xw) {
    __shared__ float xs[64][132];
    const int t   = threadIdx.x;
    const int tc  = t & 15;   // col group -> cols tc*8 .. tc*8+7
    const int tr  = t >> 4;   // row group -> rows tr, tr+16, tr+32, tr+48
    const int row0 = blockIdx.x * 64;

    // stage x tile [64][128]: 2048 float4s, 8 per thread
    #pragma unroll
    for (int i = 0; i < 8; i++) {
        int idx = t + i * 256;      // float4 index within tile
        int r   = idx >> 5;         // 32 float4 per row
        int c4  = idx & 31;
        float4 v = make_float4(0.f, 0.f, 0.f, 0.f);
        if (row0 + r < N_OUT_C)
            v = ((const float4*)x)[(size_t)(row0 + r) * 32 + c4];
        *(float4*)&xs[r][c4 * 4] = v;
    }
    __syncthreads();

    float acc[4][8];
    #pragma unroll
    for (int i = 0; i < 4; i++)
        #pragma unroll
        for (int j = 0; j < 8; j++) acc[i][j] = 0.f;

    const int c0 = tc * 8;
    #pragma unroll 4
    for (int k = 0; k < DIM; k++) {
        float4 w0 = *(const float4*)&W[k * DIM + c0];
        float4 w1 = *(const float4*)&W[k * DIM + c0 + 4];
        float wv[8] = {w0.x, w0.y, w0.z, w0.w, w1.x, w1.y, w1.z, w1.w};
        float a[4];
        #pragma unroll
        for (int i = 0; i < 4; i++) a[i] = xs[tr + 16 * i][k];
        #pragma unroll
        for (int i = 0; i < 4; i++)
            #pragma unroll
            for (int j = 0; j < 8; j++)
                acc[i][j] = fmaf(a[i], wv[j], acc[i][j]);
    }

    #pragma unroll
    for (int i = 0; i < 4; i++) {
        int r = row0 + tr + 16 * i;
        if (r < N_OUT_C) {
            float4 s0 = {acc[i][0], acc[i][1], acc[i][2], acc[i][3]};
            float4 s1 = {acc[i][4], acc[i][5], acc[i][6], acc[i][7]};
            ((float4*)xw)[(size_t)r * 32 + tc * 2]     = s0;
            ((float4*)xw)[(size_t)r * 32 + tc * 2 + 1] = s1;
        }
    }
}

// ---------------------------------------------------------------------------
// 4) scatter: out[dst] += (dinv[row]*w) * xw[row]   — one wave per edge
// ---------------------------------------------------------------------------
__global__ __launch_bounds__(256) void k_scatter(const int* __restrict__ erow,
                                                 const int* __restrict__ ecol,
                                                 const float* __restrict__ ew,
                                                 const float* __restrict__ dinv,
                                                 const float* __restrict__ xw,
                                                 float* __restrict__ out) {
    int e    = blockIdx.x * 4 + (threadIdx.x >> 6);
    int lane = threadIdx.x & 63;
    if (e >= N_EDGE_C) return;
    int   r     = erow[e];
    int   dst   = ecol[e];
    float coeff = dinv[r] * ew[e];
    const float* src = xw  + (size_t)r   * DIM;
    float*       o   = out + (size_t)dst * DIM;
    unsafeAtomicAdd(&o[lane],      coeff * src[lane]);
    unsafeAtomicAdd(&o[lane + 64], coeff * src[lane + 64]);
}

// ---------------------------------------------------------------------------
// 5) epilogue: out = relu(out + b), float4
// ---------------------------------------------------------------------------
__global__ __launch_bounds__(256) void k_epilogue(float* __restrict__ out,
                                                  const float* __restrict__ b) {
    int i = blockIdx.x * 256 + threadIdx.x;   // float4 index
    if (i < N_OUT_C * 32) {
        float4 v  = ((float4*)out)[i];
        float4 bb = ((const float4*)b)[i & 31];
        v.x = fmaxf(v.x + bb.x, 0.f);
        v.y = fmaxf(v.y + bb.y, 0.f);
        v.z = fmaxf(v.z + bb.z, 0.f);
        v.w = fmaxf(v.w + bb.w, 0.f);
        ((float4*)out)[i] = v;
    }
}

extern "C" void kernel_launch(void* const* d_in, const int* in_sizes, int n_in,
                              void* d_out, int out_size, void* d_ws, size_t ws_size,
                              hipStream_t stream) {
    const float* x    = (const float*)d_in[0];
    const int*   eidx = (const int*)d_in[1];
    const float* ew   = (const float*)d_in[2];
    const float* W    = (const float*)d_in[3];
    const float* b    = (const float*)d_in[4];
    float*       out  = (float*)d_out;

    float* deg = (float*)d_ws;                              // 50000 f32
    float* xw  = (float*)((char*)d_ws + (1 << 20));         // 50000*128 f32 = 25.6 MB

    const int* erow = eidx;
    const int* ecol = eidx + N_EDGE_C;

    hipMemsetAsync(deg, 0, N_OUT_C * sizeof(float), stream);
    hipMemsetAsync(out, 0, (size_t)N_OUT_C * DIM * sizeof(float), stream);

    k_deg     <<<(N_EDGE_C + 255) / 256, 256, 0, stream>>>(erow, ew, deg);
    k_dinv    <<<(N_OUT_C + 255) / 256, 256, 0, stream>>>(deg);
    k_gemm    <<<(N_OUT_C + 63) / 64, 256, 0, stream>>>(x, W, xw);
    k_scatter <<<(N_EDGE_C + 3) / 4, 256, 0, stream>>>(erow, ecol, ew, deg, xw, out);
    k_epilogue<<<(N_OUT_C * 32 + 255) / 256, 256, 0, stream>>>(out, b);
}